// Round 3
// baseline (503.769 us; speedup 1.0000x reference)
//
#include <hip/hip_runtime.h>
#include <hip/hip_bf16.h>

#define BB 64
#define TT 2048
#define D_ENC 512
#define D_RNN 1024
#define D_ATT 128
#define NF 32
#define KW 31

// ---------------------------------------------------------------------------
// K1: pq[b][a] = dot(hidden[b,:], query_w[a,:])   (B x 128, K=1024)
// grid (B, 32) x 256 threads; one wave per output element.
// ---------------------------------------------------------------------------
__global__ __launch_bounds__(256) void pq_kernel(
    const float* __restrict__ hid, const float* __restrict__ qw,
    float* __restrict__ pq)
{
    int b = blockIdx.x;
    int wave = threadIdx.x >> 6, lane = threadIdx.x & 63;
    int a = blockIdx.y * 4 + wave;
    const float* hrow = hid + (size_t)b * D_RNN;
    const float* qrow = qw + (size_t)a * D_RNN;
    float acc = 0.f;
#pragma unroll
    for (int j = 0; j < 4; ++j) {
        int k = (j * 64 + lane) * 4;
        float4 h = *(const float4*)(hrow + k);
        float4 q = *(const float4*)(qrow + k);
        acc += h.x * q.x + h.y * q.y + h.z * q.z + h.w * q.w;
    }
#pragma unroll
    for (int off = 32; off; off >>= 1) acc += __shfl_xor(acc, off, 64);
    if (lane == 0) pq[b * D_ATT + a] = acc;
}

// ---------------------------------------------------------------------------
// K2 (fused): conv1d -> dense -> tanh -> e=exp(alignment) -> unnormalized
// weights + exp-sum atomics -> weighted memory partial -> ctx atomics.
// No softmax max-pass needed: |alignment| <= sum|value_w| ~ 5, exp is safe.
// grid (B, T/128) x 256 threads.
// ---------------------------------------------------------------------------
__global__ __launch_bounds__(256) void fused_kernel(
    const float* __restrict__ pm,          // (B,T,128)
    const float* __restrict__ awcat,       // (B,2,T)
    const unsigned char* __restrict__ mask,// (B,T) bool
    const float* __restrict__ convw,       // (NF,2,KW)
    const float* __restrict__ ldw,         // (D_ATT,NF)
    const float* __restrict__ vw,          // (128)
    const float* __restrict__ pq,          // (B,128)
    const float* __restrict__ mem,         // (B,T,512)
    float* __restrict__ wts,               // (B,T) out: UNNORMALIZED exp
    float* __restrict__ ctx,               // (B,512) out: UNNORMALIZED ctx
    float* __restrict__ sums)              // (B) exp-sum accumulators
{
    __shared__ float s_aw[2 * 160];
    __shared__ float s_loc[128 * NF];
    __shared__ float s_e[128];
    __shared__ float4 s_p[128];

    int b = blockIdx.x;
    int t0 = blockIdx.y * 128;
    int tid = threadIdx.x;

    // stage aw_cat window [t0-15, t0+144] with zero pad (strided: 320 > 256)
    for (int i = tid; i < 320; i += 256) {
        int c = i / 160, j = i % 160;
        int tg = t0 - 15 + j;
        float v = 0.f;
        if (tg >= 0 && tg < TT) v = awcat[((size_t)b * 2 + c) * TT + tg];
        s_aw[c * 160 + j] = v;
    }
    __syncthreads();

    // ---- conv1d(2->NF, k=31, same): f = tid&31 owns one filter; sliding
    // window of 4 consecutive t's keeps taps in registers.
    {
        int f = tid & 31, g = tid >> 5;
        float w[2 * KW];
#pragma unroll
        for (int j = 0; j < 2 * KW; ++j) w[j] = convw[f * 2 * KW + j];
#pragma unroll
        for (int p = 0; p < 4; ++p) {
            int tb = g * 16 + p * 4;
            float a0 = 0.f, a1 = 0.f, a2 = 0.f, a3 = 0.f;
#pragma unroll
            for (int c = 0; c < 2; ++c) {
                float x[34];
#pragma unroll
                for (int j = 0; j < 34; ++j) x[j] = s_aw[c * 160 + tb + j];
#pragma unroll
                for (int k = 0; k < KW; ++k) {
                    float wk = w[c * KW + k];
                    a0 += x[k] * wk; a1 += x[k + 1] * wk;
                    a2 += x[k + 2] * wk; a3 += x[k + 3] * wk;
                }
            }
            s_loc[(tb + 0) * NF + f] = a0;
            s_loc[(tb + 1) * NF + f] = a1;
            s_loc[(tb + 2) * NF + f] = a2;
            s_loc[(tb + 3) * NF + f] = a3;
        }
    }
    __syncthreads();

    // ---- energies + alignment + exp. wave handles 32 t's; lane = a, a+64.
    {
        int wave = tid >> 6, lane = tid & 63;
        float pq0 = pq[b * 128 + lane], pq1 = pq[b * 128 + 64 + lane];
        float vw0 = vw[lane], vw1 = vw[64 + lane];
        float4 lA[8], lB[8];
#pragma unroll
        for (int f4 = 0; f4 < 8; ++f4) {
            lA[f4] = *(const float4*)(ldw + lane * NF + f4 * 4);
            lB[f4] = *(const float4*)(ldw + (64 + lane) * NF + f4 * 4);
        }
        const float* pmb = pm + ((size_t)b * TT + t0) * 128;
        for (int i = 0; i < 32; ++i) {
            int t = wave * 32 + i;
            float pm0 = pmb[(size_t)t * 128 + lane];
            float pm1 = pmb[(size_t)t * 128 + 64 + lane];
            float dA = 0.f, dB = 0.f;
#pragma unroll
            for (int f4 = 0; f4 < 8; ++f4) {
                float4 lv = *(const float4*)&s_loc[t * NF + f4 * 4];
                dA += lv.x * lA[f4].x + lv.y * lA[f4].y + lv.z * lA[f4].z + lv.w * lA[f4].w;
                dB += lv.x * lB[f4].x + lv.y * lB[f4].y + lv.z * lB[f4].z + lv.w * lB[f4].w;
            }
            // tanh(x) = 1 - 2/(exp(2x)+1); exact at saturation
            float xA = pq0 + pm0 + dA, xB = pq1 + pm1 + dB;
            float eA = 1.0f - __fdividef(2.0f, __expf(2.0f * xA) + 1.0f);
            float eB = 1.0f - __fdividef(2.0f, __expf(2.0f * xB) + 1.0f);
            float al = vw0 * eA + vw1 * eB;
#pragma unroll
            for (int off = 32; off; off >>= 1) al += __shfl_xor(al, off, 64);
            if (lane == 0) {
                int tt = t0 + t;
                bool m = mask[(size_t)b * TT + tt] != 0;
                float e = m ? 0.f : __expf(al);
                s_e[t] = e;
                wts[(size_t)b * TT + tt] = e;   // unnormalized; finalize divides
            }
        }
    }
    __syncthreads();

    // ---- block exp-sum -> sums[b]
    if (tid < 64) {
        float s = s_e[tid] + s_e[tid + 64];
#pragma unroll
        for (int off = 32; off; off >>= 1) s += __shfl_xor(s, off, 64);
        if (tid == 0) atomicAdd(&sums[b], s);
    }

    // ---- weighted memory partial: ctx[b][:] += sum_t e[t] * mem[b][t][:]
    {
        int d4 = tid & 127;    // float4 column (512 floats = 128 float4)
        int th = tid >> 7;     // t-parity
        const float4* mrow = (const float4*)(mem + ((size_t)b * TT + t0) * D_ENC);
        float4 acc = {0.f, 0.f, 0.f, 0.f};
        for (int i = th; i < 128; i += 2) {
            float w = s_e[i];
            float4 m = mrow[(size_t)i * 128 + d4];
            acc.x += w * m.x; acc.y += w * m.y; acc.z += w * m.z; acc.w += w * m.w;
        }
        if (th == 1) s_p[d4] = acc;
        __syncthreads();
        if (th == 0) {
            float4 o = s_p[d4];
            float* dst = ctx + (size_t)b * D_ENC + d4 * 4;
            atomicAdd(dst + 0, acc.x + o.x);
            atomicAdd(dst + 1, acc.y + o.y);
            atomicAdd(dst + 2, acc.z + o.z);
            atomicAdd(dst + 3, acc.w + o.w);
        }
    }
}

// ---------------------------------------------------------------------------
// K3: normalize weights and context by sums[b]. grid (B) x 256.
// ---------------------------------------------------------------------------
__global__ __launch_bounds__(256) void finalize_kernel(
    float* __restrict__ wts, float* __restrict__ ctx,
    const float* __restrict__ sums)
{
    int b = blockIdx.x, tid = threadIdx.x;
    float inv = __fdividef(1.0f, sums[b]);
    float* wrow = wts + (size_t)b * TT;
#pragma unroll
    for (int i = 0; i < 8; ++i) wrow[tid + i * 256] *= inv;
    float* crow = ctx + (size_t)b * D_ENC;
    crow[tid] *= inv;
    crow[tid + 256] *= inv;
}

extern "C" void kernel_launch(void* const* d_in, const int* in_sizes, int n_in,
                              void* d_out, int out_size, void* d_ws, size_t ws_size,
                              hipStream_t stream)
{
    const float* hid  = (const float*)d_in[0];
    const float* mem  = (const float*)d_in[1];
    const float* pm   = (const float*)d_in[2];
    const float* aw   = (const float*)d_in[3];
    const unsigned char* mask = (const unsigned char*)d_in[4];
    const float* qw   = (const float*)d_in[5];
    const float* vw   = (const float*)d_in[6];
    const float* cw   = (const float*)d_in[7];
    const float* ldw  = (const float*)d_in[8];

    float* out = (float*)d_out;
    float* ctx = out;                         // (B, D_ENC) first in tuple
    float* wts = out + BB * D_ENC;            // (B, T) second
    float* pq  = (float*)d_ws;                // (B, D_ATT) scratch
    float* sums = pq + BB * D_ATT;            // (B) exp-sum accumulators

    hipMemsetAsync(ctx, 0, (size_t)BB * D_ENC * sizeof(float), stream);
    hipMemsetAsync(sums, 0, (size_t)BB * sizeof(float), stream);
    pq_kernel<<<dim3(BB, 32), 256, 0, stream>>>(hid, qw, pq);
    fused_kernel<<<dim3(BB, TT / 128), 256, 0, stream>>>(
        pm, aw, mask, cw, ldw, vw, pq, mem, wts, ctx, sums);
    finalize_kernel<<<BB, 256, 0, stream>>>(wts, ctx, sums);
}

// Round 4
// 500.065 us; speedup vs baseline: 1.0074x; 1.0074x over previous
//
#include <hip/hip_runtime.h>
#include <hip/hip_bf16.h>

#define BB 64
#define TT 2048
#define D_ENC 512
#define D_RNN 1024
#define D_ATT 128
#define NF 32
#define KW 31

// ---------------------------------------------------------------------------
// K1: pq[b][a] = dot(hidden[b,:], query_w[a,:])   (B x 128, K=1024)
// grid (B, 32) x 256 threads; one wave per output element.
// ---------------------------------------------------------------------------
__global__ __launch_bounds__(256) void pq_kernel(
    const float* __restrict__ hid, const float* __restrict__ qw,
    float* __restrict__ pq)
{
    int b = blockIdx.x;
    int wave = threadIdx.x >> 6, lane = threadIdx.x & 63;
    int a = blockIdx.y * 4 + wave;
    const float* hrow = hid + (size_t)b * D_RNN;
    const float* qrow = qw + (size_t)a * D_RNN;
    float acc = 0.f;
#pragma unroll
    for (int j = 0; j < 4; ++j) {
        int k = (j * 64 + lane) * 4;
        float4 h = *(const float4*)(hrow + k);
        float4 q = *(const float4*)(qrow + k);
        acc += h.x * q.x + h.y * q.y + h.z * q.z + h.w * q.w;
    }
#pragma unroll
    for (int off = 32; off; off >>= 1) acc += __shfl_xor(acc, off, 64);
    if (lane == 0) pq[b * D_ATT + a] = acc;
}

// ---------------------------------------------------------------------------
// K2: conv1d -> dense -> tanh -> e = exp(alignment) (unnormalized) -> wts,
// exp-sum atomics. No softmax max-pass: |alignment| <= sum|vw| ~ 5.
// Conv weights in LDS (stride-63 pad: bank = (63f+x)%32 = (x-f)%32, spread)
// -- kills the w[62] register array that caused scratch demotion in R3.
// grid (B, T/128) x 256 threads.
// ---------------------------------------------------------------------------
__global__ __launch_bounds__(256, 2) void align_kernel(
    const float* __restrict__ pm,          // (B,T,128)
    const float* __restrict__ awcat,       // (B,2,T)
    const unsigned char* __restrict__ mask,// (B,T) bool
    const float* __restrict__ convw,       // (NF,2,KW)
    const float* __restrict__ ldw,         // (D_ATT,NF)
    const float* __restrict__ vw,          // (128)
    const float* __restrict__ pq,          // (B,128)
    float* __restrict__ wts,               // (B,T) out: UNNORMALIZED exp
    float* __restrict__ sums)              // (B) exp-sum accumulators
{
    __shared__ float s_aw[2 * 160];
    __shared__ float s_cw[NF * 63];
    __shared__ float s_loc[128 * NF];
    __shared__ float s_e[128];

    int b = blockIdx.x;
    int t0 = blockIdx.y * 128;
    int tid = threadIdx.x;

    // stage aw_cat window [t0-15, t0+144] with zero pad (320 > 256: strided)
    for (int i = tid; i < 320; i += 256) {
        int c = i / 160, j = i % 160;
        int tg = t0 - 15 + j;
        float v = 0.f;
        if (tg >= 0 && tg < TT) v = awcat[((size_t)b * 2 + c) * TT + tg];
        s_aw[c * 160 + j] = v;
    }
    // stage conv weights, stride 63
    for (int i = tid; i < NF * 62; i += 256) {
        int f = i / 62, j = i - f * 62;
        s_cw[f * 63 + j] = convw[i];
    }
    __syncthreads();

    // ---- conv1d(2->NF, k=31, same): f = tid&31 owns one filter; sliding
    // window of 4 consecutive t's; taps from LDS (2-way max, free).
    {
        int f = tid & 31, g = tid >> 5;
        int wbase = f * 63;
#pragma unroll
        for (int p = 0; p < 4; ++p) {
            int tb = g * 16 + p * 4;
            float a0 = 0.f, a1 = 0.f, a2 = 0.f, a3 = 0.f;
#pragma unroll
            for (int c = 0; c < 2; ++c) {
                float x[34];
#pragma unroll
                for (int j = 0; j < 34; ++j) x[j] = s_aw[c * 160 + tb + j];
#pragma unroll
                for (int k = 0; k < KW; ++k) {
                    float wk = s_cw[wbase + c * 31 + k];
                    a0 += x[k] * wk; a1 += x[k + 1] * wk;
                    a2 += x[k + 2] * wk; a3 += x[k + 3] * wk;
                }
            }
            s_loc[(tb + 0) * NF + f] = a0;
            s_loc[(tb + 1) * NF + f] = a1;
            s_loc[(tb + 2) * NF + f] = a2;
            s_loc[(tb + 3) * NF + f] = a3;
        }
    }
    __syncthreads();

    // ---- energies + alignment + exp. wave handles 32 t's; lane owns
    // a = 2*lane, 2*lane+1 (float2 pm loads, 512 B/wave/instr).
    {
        int wave = tid >> 6, lane = tid & 63;
        float2 pq2 = *(const float2*)(pq + b * 128 + 2 * lane);
        float2 vw2 = *(const float2*)(vw + 2 * lane);
        float4 lA[8], lB[8];
#pragma unroll
        for (int f4 = 0; f4 < 8; ++f4) {
            lA[f4] = *(const float4*)(ldw + (2 * lane) * NF + f4 * 4);
            lB[f4] = *(const float4*)(ldw + (2 * lane + 1) * NF + f4 * 4);
        }
        const float* pmb = pm + ((size_t)b * TT + t0) * 128;
#pragma unroll 4
        for (int i = 0; i < 32; ++i) {
            int t = wave * 32 + i;
            float2 pmv = *(const float2*)(pmb + (size_t)t * 128 + 2 * lane);
            float dA = 0.f, dB = 0.f;
#pragma unroll
            for (int f4 = 0; f4 < 8; ++f4) {
                float4 lv = *(const float4*)&s_loc[t * NF + f4 * 4];
                dA += lv.x * lA[f4].x + lv.y * lA[f4].y + lv.z * lA[f4].z + lv.w * lA[f4].w;
                dB += lv.x * lB[f4].x + lv.y * lB[f4].y + lv.z * lB[f4].z + lv.w * lB[f4].w;
            }
            // tanh(x) = 1 - 2/(exp(2x)+1); exact at saturation
            float xA = pq2.x + pmv.x + dA, xB = pq2.y + pmv.y + dB;
            float eA = 1.0f - __fdividef(2.0f, __expf(2.0f * xA) + 1.0f);
            float eB = 1.0f - __fdividef(2.0f, __expf(2.0f * xB) + 1.0f);
            float al = vw2.x * eA + vw2.y * eB;
#pragma unroll
            for (int off = 32; off; off >>= 1) al += __shfl_xor(al, off, 64);
            if (lane == 0) {
                int tt = t0 + t;
                bool m = mask[(size_t)b * TT + tt] != 0;
                float e = m ? 0.f : __expf(al);
                s_e[t] = e;
                wts[(size_t)b * TT + tt] = e;   // finalize divides by sums[b]
            }
        }
    }
    __syncthreads();

    // ---- block exp-sum -> sums[b]
    if (tid < 64) {
        float s = s_e[tid] + s_e[tid + 64];
#pragma unroll
        for (int off = 32; off; off >>= 1) s += __shfl_xor(s, off, 64);
        if (tid == 0) atomicAdd(&sums[b], s);
    }
}

// ---------------------------------------------------------------------------
// K3: context partials: ctx[b][:] += sum_t e[t]*mem[b][t][:].  grid (B,32),
// 64 t's per block; 8x-unrolled float4 loads -> 8 KB in flight per wave,
// 32 waves/CU (tiny LDS, low VGPR) => HBM-bound on the 268 MB stream.
// ---------------------------------------------------------------------------
__global__ __launch_bounds__(256) void ctx_kernel(
    const float* __restrict__ mem, const float* __restrict__ wts,
    float* __restrict__ out)
{
    int b = blockIdx.x, c = blockIdx.y;
    int tid = threadIdx.x;
    int d4 = tid & 127;    // float4 column (512 floats = 128 float4)
    int th = tid >> 7;     // t-parity
    int t0 = c * 64;
    __shared__ float s_w[64];
    __shared__ float4 s_p[128];
    if (tid < 64) s_w[tid] = wts[(size_t)b * TT + t0 + tid];
    __syncthreads();
    const float4* mrow = (const float4*)(mem + ((size_t)b * TT + t0) * D_ENC);
    float4 acc = {0.f, 0.f, 0.f, 0.f};
#pragma unroll 8
    for (int ii = 0; ii < 32; ++ii) {
        int i = ii * 2 + th;
        float w = s_w[i];
        float4 m = mrow[(size_t)i * 128 + d4];
        acc.x += w * m.x; acc.y += w * m.y; acc.z += w * m.z; acc.w += w * m.w;
    }
    if (th == 1) s_p[d4] = acc;
    __syncthreads();
    if (th == 0) {
        float4 o = s_p[d4];
        float* dst = out + (size_t)b * D_ENC + d4 * 4;
        atomicAdd(dst + 0, acc.x + o.x);
        atomicAdd(dst + 1, acc.y + o.y);
        atomicAdd(dst + 2, acc.z + o.z);
        atomicAdd(dst + 3, acc.w + o.w);
    }
}

// ---------------------------------------------------------------------------
// K4: normalize weights and context by sums[b]. grid (B) x 256.
// ---------------------------------------------------------------------------
__global__ __launch_bounds__(256) void finalize_kernel(
    float* __restrict__ wts, float* __restrict__ ctx,
    const float* __restrict__ sums)
{
    int b = blockIdx.x, tid = threadIdx.x;
    float inv = __fdividef(1.0f, sums[b]);
    float* wrow = wts + (size_t)b * TT;
#pragma unroll
    for (int i = 0; i < 8; ++i) wrow[tid + i * 256] *= inv;
    float* crow = ctx + (size_t)b * D_ENC;
    crow[tid] *= inv;
    crow[tid + 256] *= inv;
}

extern "C" void kernel_launch(void* const* d_in, const int* in_sizes, int n_in,
                              void* d_out, int out_size, void* d_ws, size_t ws_size,
                              hipStream_t stream)
{
    const float* hid  = (const float*)d_in[0];
    const float* mem  = (const float*)d_in[1];
    const float* pm   = (const float*)d_in[2];
    const float* aw   = (const float*)d_in[3];
    const unsigned char* mask = (const unsigned char*)d_in[4];
    const float* qw   = (const float*)d_in[5];
    const float* vw   = (const float*)d_in[6];
    const float* cw   = (const float*)d_in[7];
    const float* ldw  = (const float*)d_in[8];

    float* out = (float*)d_out;
    float* ctx = out;                         // (B, D_ENC) first in tuple
    float* wts = out + BB * D_ENC;            // (B, T) second
    float* pq  = (float*)d_ws;                // (B, D_ATT) scratch
    float* sums = pq + BB * D_ATT;            // (B) exp-sum accumulators

    hipMemsetAsync(ctx, 0, (size_t)BB * D_ENC * sizeof(float), stream);
    hipMemsetAsync(sums, 0, (size_t)BB * sizeof(float), stream);
    pq_kernel<<<dim3(BB, 32), 256, 0, stream>>>(hid, qw, pq);
    align_kernel<<<dim3(BB, TT / 128), 256, 0, stream>>>(
        pm, aw, mask, cw, ldw, vw, pq, wts, sums);
    ctx_kernel<<<dim3(BB, 32), 256, 0, stream>>>(mem, wts, ctx);
    finalize_kernel<<<BB, 256, 0, stream>>>(wts, ctx, sums);
}